// Round 3
// baseline (575.856 us; speedup 1.0000x reference)
//
#include <hip/hip_runtime.h>
#include <stdint.h>

#define TSTEPS 512
#define BATCH  4096
// R3: 512 blocks x 256 threads, each block owns 8 batch rows (M=16 MFMA with
// the 8 valid rows placed at m&3 in {0,1} so every lane owns exactly 2 valid
// accumulator rows). 2 blocks/CU -> 2 waves/SIMD: MFMA of one wave overlaps
// VALU of the other, barrier drains hidden by the sibling block.

typedef __attribute__((ext_vector_type(8))) short bf16x8;
typedef __attribute__((ext_vector_type(4))) float f32x4;
typedef __attribute__((ext_vector_type(2))) float f32x2;

__device__ __forceinline__ short f2bf(float f) {
    uint32_t u = __float_as_uint(f);
    uint32_t r = (u + 0x7fffu + ((u >> 16) & 1u)) >> 16;
    return (short)r;
}
__device__ __forceinline__ float bf2f(short s) {
    return __uint_as_float(((uint32_t)(uint16_t)s) << 16);
}
__device__ __forceinline__ float fast_rcp(float x) { return __builtin_amdgcn_rcpf(x); }
__device__ __forceinline__ float sigmoid_f(float x) { return fast_rcp(1.0f + __expf(-x)); }
__device__ __forceinline__ float tanh_f(float x) { return 1.0f - 2.0f * fast_rcp(1.0f + __expf(2.0f * x)); }

__global__ __launch_bounds__(256, 2) void gru_fused(
    const float* __restrict__ x,     // [T,B,2]
    const float* __restrict__ Wih0,  // [192,2]
    const float* __restrict__ Whh0,  // [192,64]
    const float* __restrict__ bih0,  // [192]
    const float* __restrict__ bhh0,  // [192]
    const float* __restrict__ Wih1,  // [192,64]
    const float* __restrict__ Whh1,  // [192,64]
    const float* __restrict__ bih1,  // [192]
    const float* __restrict__ bhh1,  // [192]
    const float* __restrict__ Wp,    // [128]
    const float* __restrict__ bp,    // [1]
    float* __restrict__ out)         // [B]
{
    const int tid = threadIdx.x;
    const int w   = tid >> 6;    // wave 0..3
    const int l   = tid & 63;    // lane
    const int lm  = l & 15;      // A row m / n-col within tile
    const int lq  = l >> 4;      // quad
    const int b0  = blockIdx.x * 8;
    const int j   = w * 16 + lm; // hidden index this lane owns in elementwise

    // h state, bf16, A-layout: [m][64 + 8 pad] shorts, m = 0..15.
    // Batch row r (0..7) lives at m = (r>>1)*4 + (r&1); rows with m&3>=2 stay 0.
    __shared__ short h0A[2][16 * 72];
    __shared__ short h1A[2][16 * 72];
    __shared__ float Pf[8][64];

    // Zero BOTH parities (padded rows must stay zero forever).
    for (int idx = tid; idx < 2 * 16 * 72; idx += 256) {
        ((short*)h0A)[idx] = 0;
        ((short*)h1A)[idx] = 0;
    }

    // ---- B fragments (weights) in registers, hi/lo bf16 split ----
    // lane holds k = q*32 + lq*8 + i, n = g*64 + w*16 + lm
    bf16x8 w0hi[3][2], w0lo[3][2];   // Whh0
    bf16x8 w1hi[3][2], w1lo[3][2];   // Wih1
    bf16x8 w2hi[3][2], w2lo[3][2];   // Whh1
#pragma unroll
    for (int g = 0; g < 3; ++g) {
        const int row = g * 64 + w * 16 + lm;
#pragma unroll
        for (int q = 0; q < 2; ++q) {
            const int c0 = q * 32 + lq * 8;
            const float* p0 = Whh0 + row * 64 + c0;
            const float* p1 = Wih1 + row * 64 + c0;
            const float* p2 = Whh1 + row * 64 + c0;
            bf16x8 v0h, v0l, v1h, v1l, v2h, v2l;
#pragma unroll
            for (int i = 0; i < 8; ++i) {
                float f0 = p0[i], f1 = p1[i], f2 = p2[i];
                short h0s = f2bf(f0), h1s = f2bf(f1), h2s = f2bf(f2);
                v0h[i] = h0s; v0l[i] = f2bf(f0 - bf2f(h0s));
                v1h[i] = h1s; v1l[i] = f2bf(f1 - bf2f(h1s));
                v2h[i] = h2s; v2l[i] = f2bf(f2 - bf2f(h2s));
            }
            w0hi[g][q] = v0h; w0lo[g][q] = v0l;
            w1hi[g][q] = v1h; w1lo[g][q] = v1l;
            w2hi[g][q] = v2h; w2lo[g][q] = v2l;
        }
    }

    // per-lane scalar constants (fp32, exact; bias pairs pre-summed)
    const float wi_r0 = Wih0[j * 2 + 0],         wi_r1 = Wih0[j * 2 + 1];
    const float wi_z0 = Wih0[(64 + j) * 2 + 0],  wi_z1 = Wih0[(64 + j) * 2 + 1];
    const float wi_n0 = Wih0[(128 + j) * 2 + 0], wi_n1 = Wih0[(128 + j) * 2 + 1];
    const float br0 = bih0[j] + bhh0[j];
    const float bz0 = bih0[64 + j] + bhh0[64 + j];
    const float bi0_n = bih0[128 + j], bh0_n = bhh0[128 + j];
    const float br1 = bih1[j] + bhh1[j];
    const float bz1 = bih1[64 + j] + bhh1[64 + j];
    const float bi1_n = bih1[128 + j], bh1_n = bhh1[128 + j];

    float h0r[2] = {0.f, 0.f};
    float h1r[2] = {0.f, 0.f};

    // x for current step (prefetched one step ahead); 2 rows per lane.
    f32x2 xc[2], xnb[2];
#pragma unroll
    for (int i = 0; i < 2; ++i) {
        const int b = b0 + lq * 2 + i;
        xc[i] = *(const f32x2*)(x + (size_t)b * 2);
    }

    __syncthreads();  // LDS zeroed

    const int aoff = lm * 72 + lq * 8;  // shorts; +32 for K-half 1

    // 513 iterations: iter t produces h0(t) (t<512) and h1(t-1) (t>0).
    for (int t = 0; t <= TSTEPS; ++t) {
        const int pr = t & 1;
        const int pw = pr ^ 1;

        // A-fragments: h0(t-1) feeds hg0(t) AND xg1(t-1); h1(t-2) feeds hg1(t-1).
        bf16x8 a00 = *(const bf16x8*)&h0A[pr][aoff];
        bf16x8 a01 = *(const bf16x8*)&h0A[pr][aoff + 32];
        bf16x8 a10 = *(const bf16x8*)&h1A[pr][aoff];
        bf16x8 a11 = *(const bf16x8*)&h1A[pr][aoff + 32];

        // prefetch x for t+1 (branch-free wrap; overlaps the MFMA block)
        {
            const int tn = (t + 1) & (TSTEPS - 1);
#pragma unroll
            for (int i = 0; i < 2; ++i) {
                const int b = b0 + lq * 2 + i;
                xnb[i] = *(const f32x2*)(x + (size_t)(tn * BATCH + b) * 2);
            }
        }

        // All 9 output tiles independent: hg0(t), xg1(t-1), hg1(t-1).
        f32x4 hg0[3], hg1[3], xg1[3];
#pragma unroll
        for (int g = 0; g < 3; ++g) {
            const f32x4 z4 = {0.f, 0.f, 0.f, 0.f};
            f32x4 c;
            c = __builtin_amdgcn_mfma_f32_16x16x32_bf16(a00, w0hi[g][0], z4, 0, 0, 0);
            c = __builtin_amdgcn_mfma_f32_16x16x32_bf16(a01, w0hi[g][1], c, 0, 0, 0);
            c = __builtin_amdgcn_mfma_f32_16x16x32_bf16(a00, w0lo[g][0], c, 0, 0, 0);
            hg0[g] = __builtin_amdgcn_mfma_f32_16x16x32_bf16(a01, w0lo[g][1], c, 0, 0, 0);
            f32x4 d;
            d = __builtin_amdgcn_mfma_f32_16x16x32_bf16(a00, w1hi[g][0], z4, 0, 0, 0);
            d = __builtin_amdgcn_mfma_f32_16x16x32_bf16(a01, w1hi[g][1], d, 0, 0, 0);
            d = __builtin_amdgcn_mfma_f32_16x16x32_bf16(a00, w1lo[g][0], d, 0, 0, 0);
            xg1[g] = __builtin_amdgcn_mfma_f32_16x16x32_bf16(a01, w1lo[g][1], d, 0, 0, 0);
            f32x4 e;
            e = __builtin_amdgcn_mfma_f32_16x16x32_bf16(a10, w2hi[g][0], z4, 0, 0, 0);
            e = __builtin_amdgcn_mfma_f32_16x16x32_bf16(a11, w2hi[g][1], e, 0, 0, 0);
            e = __builtin_amdgcn_mfma_f32_16x16x32_bf16(a10, w2lo[g][0], e, 0, 0, 0);
            hg1[g] = __builtin_amdgcn_mfma_f32_16x16x32_bf16(a11, w2lo[g][1], e, 0, 0, 0);
        }

        // layer 0 elementwise -> h0(t); acc reg i in {0,1} = batch row lq*2+i,
        // LDS row m = lq*4 + i.
        if (t < TSTEPS) {
#pragma unroll
            for (int i = 0; i < 2; ++i) {
                const float x0 = xc[i].x, x1 = xc[i].y;
                const float gr = fmaf(wi_r0, x0, fmaf(wi_r1, x1, br0 + hg0[0][i]));
                const float gz = fmaf(wi_z0, x0, fmaf(wi_z1, x1, bz0 + hg0[1][i]));
                const float hn = hg0[2][i] + bh0_n;
                const float gn = fmaf(wi_n0, x0, fmaf(wi_n1, x1, bi0_n));
                const float r = sigmoid_f(gr);
                const float z = sigmoid_f(gz);
                const float n = tanh_f(fmaf(r, hn, gn));
                const float h = fmaf(z, h0r[i] - n, n);
                h0r[i] = h;
                h0A[pw][(lq * 4 + i) * 72 + j] = f2bf(h);
            }
        }

        // layer 1 elementwise -> h1(t-1)
        if (t > 0) {
#pragma unroll
            for (int i = 0; i < 2; ++i) {
                const float r = sigmoid_f(xg1[0][i] + br1 + hg1[0][i]);
                const float z = sigmoid_f(xg1[1][i] + bz1 + hg1[1][i]);
                const float n = tanh_f(fmaf(r, hg1[2][i] + bh1_n, xg1[2][i] + bi1_n));
                const float h = fmaf(z, h1r[i] - n, n);
                h1r[i] = h;
                h1A[pw][(lq * 4 + i) * 72 + j] = f2bf(h);
            }
        }

#pragma unroll
        for (int i = 0; i < 2; ++i) xc[i] = xnb[i];
        __syncthreads();   // ONE barrier per step
    }

    // ---- final projection: out[b] = sum_j Wp[j]*h0f + Wp[64+j]*h1f + bp ----
    const float wp0 = Wp[j], wp1 = Wp[64 + j];
#pragma unroll
    for (int i = 0; i < 2; ++i)
        Pf[lq * 2 + i][j] = fmaf(wp0, h0r[i], wp1 * h1r[i]);
    __syncthreads();
    if (tid < 8) {
        float s = bp[0];
#pragma unroll 8
        for (int k = 0; k < 64; ++k) s += Pf[tid][k];
        out[b0 + tid] = s;
    }
}

extern "C" void kernel_launch(void* const* d_in, const int* in_sizes, int n_in,
                              void* d_out, int out_size, void* d_ws, size_t ws_size,
                              hipStream_t stream) {
    (void)in_sizes; (void)n_in; (void)out_size; (void)d_ws; (void)ws_size;
    gru_fused<<<dim3(BATCH / 8), dim3(256), 0, stream>>>(
        (const float*)d_in[0], (const float*)d_in[1], (const float*)d_in[2],
        (const float*)d_in[3], (const float*)d_in[4], (const float*)d_in[5],
        (const float*)d_in[6], (const float*)d_in[7], (const float*)d_in[8],
        (const float*)d_in[9], (const float*)d_in[10], (float*)d_out);
}

// Round 4
// 431.226 us; speedup vs baseline: 1.3354x; 1.3354x over previous
//
#include <hip/hip_runtime.h>
#include <stdint.h>

#define TSTEPS 512
#define BATCH  4096
// R4: 256 blocks x 512 threads (8 waves), 16 batch rows/block.
// Wave specialization: waves 0-3 = layer 0 (hg0, 12 MFMA + EW0),
// waves 4-7 = layer 1 (xg1+hg1, 24 MFMA + EW1). Waves i and i+4 share a SIMD
// -> 2 waves/SIMD with full per-wave register budget (no R3 spills).
// Software pipeline (iter t: h0(t) and h1(t-1)) keeps the roles independent;
// one barrier per step, counts matched across the divergent paths.

typedef __attribute__((ext_vector_type(8))) short bf16x8;
typedef __attribute__((ext_vector_type(4))) float f32x4;
typedef __attribute__((ext_vector_type(2))) float f32x2;

__device__ __forceinline__ short f2bf(float f) {
    uint32_t u = __float_as_uint(f);
    uint32_t r = (u + 0x7fffu + ((u >> 16) & 1u)) >> 16;
    return (short)r;
}
__device__ __forceinline__ float bf2f(short s) {
    return __uint_as_float(((uint32_t)(uint16_t)s) << 16);
}
__device__ __forceinline__ float fast_rcp(float x) { return __builtin_amdgcn_rcpf(x); }
__device__ __forceinline__ float sigmoid_f(float x) { return fast_rcp(1.0f + __expf(-x)); }
__device__ __forceinline__ float tanh_f(float x) { return 1.0f - 2.0f * fast_rcp(1.0f + __expf(2.0f * x)); }

__global__ __launch_bounds__(512, 2) void gru_fused(
    const float* __restrict__ x,     // [T,B,2]
    const float* __restrict__ Wih0,  // [192,2]
    const float* __restrict__ Whh0,  // [192,64]
    const float* __restrict__ bih0,  // [192]
    const float* __restrict__ bhh0,  // [192]
    const float* __restrict__ Wih1,  // [192,64]
    const float* __restrict__ Whh1,  // [192,64]
    const float* __restrict__ bih1,  // [192]
    const float* __restrict__ bhh1,  // [192]
    const float* __restrict__ Wp,    // [128]
    const float* __restrict__ bp,    // [1]
    float* __restrict__ out)         // [B]
{
    const int tid  = threadIdx.x;
    const int wv   = tid >> 6;      // wave 0..7
    const int isL0 = (wv < 4);
    const int w4   = wv & 3;
    const int l    = tid & 63;
    const int lm   = l & 15;        // A row m / n-col within tile
    const int lq   = l >> 4;        // quad
    const int b0   = blockIdx.x * 16;
    const int j    = w4 * 16 + lm;  // hidden index this lane owns

    // h state, bf16, A-layout: [m][64+8 pad] shorts; stride 144 B (16B-aligned,
    // 2-way bank aliasing = free).
    __shared__ short h0A[2][16 * 72];
    __shared__ short h1A[2][16 * 72];
    __shared__ float Pf[16][64];

    for (int idx = tid; idx < 2 * 16 * 72; idx += 512) {
        ((short*)h0A)[idx] = 0;
        ((short*)h1A)[idx] = 0;
    }
    __syncthreads();

    const int aoff = lm * 72 + lq * 8;  // shorts; +32 for K-half 1

    if (isL0) {
        // ================= layer-0 waves =================
        // Whh0 B-fragments, hi/lo bf16 split: k = q*32+lq*8+i, n = g*64+j
        bf16x8 whi[3][2], wlo[3][2];
#pragma unroll
        for (int g = 0; g < 3; ++g) {
            const int row = g * 64 + j;
#pragma unroll
            for (int q = 0; q < 2; ++q) {
                const float* p = Whh0 + row * 64 + q * 32 + lq * 8;
                bf16x8 vh, vl;
#pragma unroll
                for (int i = 0; i < 8; ++i) {
                    float f = p[i];
                    short hs = f2bf(f);
                    vh[i] = hs; vl[i] = f2bf(f - bf2f(hs));
                }
                whi[g][q] = vh; wlo[g][q] = vl;
            }
        }
        const float wi_r0 = Wih0[j * 2 + 0],         wi_r1 = Wih0[j * 2 + 1];
        const float wi_z0 = Wih0[(64 + j) * 2 + 0],  wi_z1 = Wih0[(64 + j) * 2 + 1];
        const float wi_n0 = Wih0[(128 + j) * 2 + 0], wi_n1 = Wih0[(128 + j) * 2 + 1];
        const float br0 = bih0[j] + bhh0[j];
        const float bz0 = bih0[64 + j] + bhh0[64 + j];
        const float bi0_n = bih0[128 + j], bh0_n = bhh0[128 + j];

        float h0r[4] = {0.f, 0.f, 0.f, 0.f};
        f32x2 xc[4], xnb[4];
#pragma unroll
        for (int i = 0; i < 4; ++i)
            xc[i] = *(const f32x2*)(x + (size_t)(b0 + lq * 4 + i) * 2);

        for (int t = 0; t <= TSTEPS; ++t) {
            const int pr = t & 1, pw = pr ^ 1;
            bf16x8 a00 = *(const bf16x8*)&h0A[pr][aoff];
            bf16x8 a01 = *(const bf16x8*)&h0A[pr][aoff + 32];

            const int tn = (t + 1) & (TSTEPS - 1);
#pragma unroll
            for (int i = 0; i < 4; ++i)
                xnb[i] = *(const f32x2*)(x + (size_t)(tn * BATCH + b0 + lq * 4 + i) * 2);

            f32x4 hg0[3];
#pragma unroll
            for (int g = 0; g < 3; ++g) {
                const f32x4 z4 = {0.f, 0.f, 0.f, 0.f};
                f32x4 c;
                c = __builtin_amdgcn_mfma_f32_16x16x32_bf16(a00, whi[g][0], z4, 0, 0, 0);
                c = __builtin_amdgcn_mfma_f32_16x16x32_bf16(a01, whi[g][1], c, 0, 0, 0);
                c = __builtin_amdgcn_mfma_f32_16x16x32_bf16(a00, wlo[g][0], c, 0, 0, 0);
                hg0[g] = __builtin_amdgcn_mfma_f32_16x16x32_bf16(a01, wlo[g][1], c, 0, 0, 0);
            }

            if (t < TSTEPS) {
#pragma unroll
                for (int i = 0; i < 4; ++i) {
                    const float x0 = xc[i].x, x1 = xc[i].y;
                    const float gr = fmaf(wi_r0, x0, fmaf(wi_r1, x1, br0 + hg0[0][i]));
                    const float gz = fmaf(wi_z0, x0, fmaf(wi_z1, x1, bz0 + hg0[1][i]));
                    const float hn = hg0[2][i] + bh0_n;
                    const float gn = fmaf(wi_n0, x0, fmaf(wi_n1, x1, bi0_n));
                    const float r = sigmoid_f(gr);
                    const float z = sigmoid_f(gz);
                    const float n = tanh_f(fmaf(r, hn, gn));
                    const float h = fmaf(z, h0r[i] - n, n);
                    h0r[i] = h;
                    h0A[pw][(lq * 4 + i) * 72 + j] = f2bf(h);
                }
            }
#pragma unroll
            for (int i = 0; i < 4; ++i) xc[i] = xnb[i];
            __syncthreads();   // barrier #1..513
        }

        const float wp0 = Wp[j];
#pragma unroll
        for (int i = 0; i < 4; ++i)
            Pf[lq * 4 + i][j] = wp0 * h0r[i];
        __syncthreads();       // barrier #514
        __syncthreads();       // barrier #515
    } else {
        // ================= layer-1 waves =================
        // Wih1 (xg1) and Whh1 (hg1) B-fragments, hi/lo split
        bf16x8 w1hi[3][2], w1lo[3][2], w2hi[3][2], w2lo[3][2];
#pragma unroll
        for (int g = 0; g < 3; ++g) {
            const int row = g * 64 + j;
#pragma unroll
            for (int q = 0; q < 2; ++q) {
                const float* p1 = Wih1 + row * 64 + q * 32 + lq * 8;
                const float* p2 = Whh1 + row * 64 + q * 32 + lq * 8;
                bf16x8 v1h, v1l, v2h, v2l;
#pragma unroll
                for (int i = 0; i < 8; ++i) {
                    float f1 = p1[i], f2 = p2[i];
                    short s1 = f2bf(f1), s2 = f2bf(f2);
                    v1h[i] = s1; v1l[i] = f2bf(f1 - bf2f(s1));
                    v2h[i] = s2; v2l[i] = f2bf(f2 - bf2f(s2));
                }
                w1hi[g][q] = v1h; w1lo[g][q] = v1l;
                w2hi[g][q] = v2h; w2lo[g][q] = v2l;
            }
        }
        const float br1 = bih1[j] + bhh1[j];
        const float bz1 = bih1[64 + j] + bhh1[64 + j];
        const float bi1_n = bih1[128 + j], bh1_n = bhh1[128 + j];

        float h1r[4] = {0.f, 0.f, 0.f, 0.f};

        for (int t = 0; t <= TSTEPS; ++t) {
            const int pr = t & 1, pw = pr ^ 1;
            bf16x8 a00 = *(const bf16x8*)&h0A[pr][aoff];
            bf16x8 a01 = *(const bf16x8*)&h0A[pr][aoff + 32];
            bf16x8 a10 = *(const bf16x8*)&h1A[pr][aoff];
            bf16x8 a11 = *(const bf16x8*)&h1A[pr][aoff + 32];

            f32x4 xg1[3], hg1[3];
#pragma unroll
            for (int g = 0; g < 3; ++g) {
                const f32x4 z4 = {0.f, 0.f, 0.f, 0.f};
                f32x4 d;
                d = __builtin_amdgcn_mfma_f32_16x16x32_bf16(a00, w1hi[g][0], z4, 0, 0, 0);
                d = __builtin_amdgcn_mfma_f32_16x16x32_bf16(a01, w1hi[g][1], d, 0, 0, 0);
                d = __builtin_amdgcn_mfma_f32_16x16x32_bf16(a00, w1lo[g][0], d, 0, 0, 0);
                xg1[g] = __builtin_amdgcn_mfma_f32_16x16x32_bf16(a01, w1lo[g][1], d, 0, 0, 0);
                f32x4 e;
                e = __builtin_amdgcn_mfma_f32_16x16x32_bf16(a10, w2hi[g][0], z4, 0, 0, 0);
                e = __builtin_amdgcn_mfma_f32_16x16x32_bf16(a11, w2hi[g][1], e, 0, 0, 0);
                e = __builtin_amdgcn_mfma_f32_16x16x32_bf16(a10, w2lo[g][0], e, 0, 0, 0);
                hg1[g] = __builtin_amdgcn_mfma_f32_16x16x32_bf16(a11, w2lo[g][1], e, 0, 0, 0);
            }

            if (t > 0) {
#pragma unroll
                for (int i = 0; i < 4; ++i) {
                    const float r = sigmoid_f(xg1[0][i] + br1 + hg1[0][i]);
                    const float z = sigmoid_f(xg1[1][i] + bz1 + hg1[1][i]);
                    const float n = tanh_f(fmaf(r, hg1[2][i] + bh1_n, xg1[2][i] + bi1_n));
                    const float h = fmaf(z, h1r[i] - n, n);
                    h1r[i] = h;
                    h1A[pw][(lq * 4 + i) * 72 + j] = f2bf(h);
                }
            }
            __syncthreads();   // barrier #1..513
        }

        __syncthreads();       // barrier #514 (Pf written by layer-0 waves)
        const float wp1 = Wp[64 + j];
#pragma unroll
        for (int i = 0; i < 4; ++i)
            Pf[lq * 4 + i][j] += wp1 * h1r[i];
        __syncthreads();       // barrier #515
    }

    // ---- final reduce: out[b] = sum_j Pf[row][j] + bp ----
    if (tid < 16) {
        float s = bp[0];
#pragma unroll 8
        for (int k = 0; k < 64; ++k) s += Pf[tid][k];
        out[b0 + tid] = s;
    }
}

extern "C" void kernel_launch(void* const* d_in, const int* in_sizes, int n_in,
                              void* d_out, int out_size, void* d_ws, size_t ws_size,
                              hipStream_t stream) {
    (void)in_sizes; (void)n_in; (void)out_size; (void)d_ws; (void)ws_size;
    gru_fused<<<dim3(BATCH / 16), dim3(512), 0, stream>>>(
        (const float*)d_in[0], (const float*)d_in[1], (const float*)d_in[2],
        (const float*)d_in[3], (const float*)d_in[4], (const float*)d_in[5],
        (const float*)d_in[6], (const float*)d_in[7], (const float*)d_in[8],
        (const float*)d_in[9], (const float*)d_in[10], (float*)d_out);
}